// Round 8
// baseline (212.485 us; speedup 1.0000x reference)
//
#include <hip/hip_runtime.h>
#include <stdint.h>

#define TSEQ 2048
#define NB 2
#define EMB 1024
#define NHEAD 16
#define HDIM 64
#define KSPLIT 4
#define NT (TSEQ / KSPLIT / 64)   // 8 key-tiles per block
// 0.125 (D^-0.5) * log2(e), folded into Q at the in-proj epilogue
#define QSCALE 0.18033688f

typedef __bf16 bf16x8 __attribute__((ext_vector_type(8)));
typedef __bf16 bf16x4 __attribute__((ext_vector_type(4)));
typedef float f32x4 __attribute__((ext_vector_type(4)));

// async 16B global->LDS. lds base must be wave-uniform; HW scatters lane*16.
__device__ __forceinline__ void gload_lds16(const void* g, void* lds) {
    __builtin_amdgcn_global_load_lds(
        (const __attribute__((address_space(1))) unsigned int*)g,
        (__attribute__((address_space(3))) unsigned int*)lds, 16, 0, 0);
}

// ---------------------------------------------------------------------------
// merged prep: bx<128 -> weight transpose+cvt (w_in 96, w_out 32);
// bx>=128 -> x f32->bf16 copy. block (32,8), grid (256, 32).
// ---------------------------------------------------------------------------
__global__ __launch_bounds__(256) void prep_kernel(
    const float* __restrict__ x, const float* __restrict__ w_in,
    const float* __restrict__ w_out,
    __bf16* __restrict__ xb, __bf16* __restrict__ wiT, __bf16* __restrict__ whT)
{
    __shared__ float tile[32][33];
    int bx = blockIdx.x;
    const int by = blockIdx.y;
    const int tx = threadIdx.x, ty = threadIdx.y;
    if (bx >= 128) {                    // x cvt path: 128x32 chunks of 1024
        const int tid = ty * 32 + tx;
        const size_t base =
            (((size_t)by * 128 + (bx - 128)) * 256 + tid) * 4;
        float4 v = *(const float4*)(x + base);
        bf16x4 o = { (__bf16)v.x, (__bf16)v.y, (__bf16)v.z, (__bf16)v.w };
        *(bf16x4*)(xb + base) = o;
        return;
    }
    const float* src; __bf16* dst; int sn;
    if (bx < 96) { src = w_in;  dst = wiT; sn = 3072; }
    else         { bx -= 96; src = w_out; dst = whT; sn = 1024; }
    #pragma unroll
    for (int i = 0; i < 4; ++i)
        tile[ty + i * 8][tx] = src[(size_t)(by * 32 + ty + i * 8) * sn + bx * 32 + tx];
    __syncthreads();
    #pragma unroll
    for (int i = 0; i < 4; ++i) {
        float v = tile[tx][ty + i * 8];
        dst[(size_t)(bx * 32 + ty + i * 8) * 1024 + by * 32 + tx] = (__bf16)v;
    }
}

// ---------------------------------------------------------------------------
// bf16 MFMA GEMM for in-projection. 128x128 tile, BK=64. Epilogue scatters
// Q (pre-scaled by QSCALE), K, V -- ALL coalesced [bh][t][d]. grid (24, 32)
// ---------------------------------------------------------------------------
__global__ __launch_bounds__(256) void gemm_qkv_kernel(
    const __bf16* __restrict__ A, const __bf16* __restrict__ BT,
    const float* __restrict__ bias,
    __bf16* __restrict__ Oq, __bf16* __restrict__ Ok, __bf16* __restrict__ Ov)
{
    __shared__ __align__(16) __bf16 As[128 * 64];
    __shared__ __align__(16) __bf16 Bs[128 * 64];
    const int tid = threadIdx.x;
    const int wave = tid >> 6, lane = tid & 63;
    const int l16 = lane & 15, quad = lane >> 4;
    const int wm = wave >> 1, wn = wave & 1;
    const int m0 = blockIdx.y * 128, n0 = blockIdx.x * 128;

    f32x4 acc[4][4];
    #pragma unroll
    for (int mt = 0; mt < 4; ++mt)
        #pragma unroll
        for (int nt = 0; nt < 4; ++nt)
            #pragma unroll
            for (int r = 0; r < 4; ++r) acc[mt][nt][r] = 0.f;

    int smrow[4], schunk[4], sbase[4];
    #pragma unroll
    for (int i = 0; i < 4; ++i) {
        int linear = (wave * 4 + i) * 64 + lane;
        smrow[i] = linear >> 3;
        schunk[i] = (linear & 7) ^ (smrow[i] & 7);
        sbase[i] = (wave * 4 + i) * 512;
    }

    for (int k0 = 0; k0 < 1024; k0 += 64) {
        #pragma unroll
        for (int i = 0; i < 4; ++i) {
            gload_lds16(A + (size_t)(m0 + smrow[i]) * 1024 + k0 + schunk[i] * 8,
                        As + sbase[i]);
            gload_lds16(BT + (size_t)(n0 + smrow[i]) * 1024 + k0 + schunk[i] * 8,
                        Bs + sbase[i]);
        }
        __syncthreads();
        #pragma unroll
        for (int kk = 0; kk < 2; ++kk) {
            bf16x8 am[4], bn[4];
            #pragma unroll
            for (int mt = 0; mt < 4; ++mt) {
                int row = wm * 64 + mt * 16 + l16;
                int c = (kk * 4 + quad) ^ (row & 7);
                am[mt] = *(const bf16x8*)(As + row * 64 + c * 8);
            }
            #pragma unroll
            for (int nt = 0; nt < 4; ++nt) {
                int row = wn * 64 + nt * 16 + l16;
                int c = (kk * 4 + quad) ^ (row & 7);
                bn[nt] = *(const bf16x8*)(Bs + row * 64 + c * 8);
            }
            #pragma unroll
            for (int mt = 0; mt < 4; ++mt)
                #pragma unroll
                for (int nt = 0; nt < 4; ++nt)
                    acc[mt][nt] = __builtin_amdgcn_mfma_f32_16x16x32_bf16(
                        am[mt], bn[nt], acc[mt][nt], 0, 0, 0);
        }
        __syncthreads();
    }

    #pragma unroll
    for (int nt = 0; nt < 4; ++nt) {
        const int col = n0 + wn * 64 + nt * 16 + l16;
        const float bv = bias[col];
        const int sec = col >> 10, f = col & 1023;
        const int h = f >> 6, d = f & 63;
        #pragma unroll
        for (int mt = 0; mt < 4; ++mt)
            #pragma unroll
            for (int r = 0; r < 4; ++r) {
                const int row = m0 + wm * 64 + mt * 16 + quad * 4 + r;
                float v = acc[mt][nt][r] + bv;
                const int t = row >> 1, b = row & 1;
                const int bh = b * NHEAD + h;
                const size_t idx = ((size_t)bh * TSEQ + t) * HDIM + d;
                if (sec == 0)
                    Oq[idx] = (__bf16)(v * QSCALE);
                else if (sec == 1)
                    Ok[idx] = (__bf16)v;
                else
                    Ov[idx] = (__bf16)v;   // coalesced; vtrans transposes
            }
    }
}

// ---------------------------------------------------------------------------
// V [bh][t][d] -> Vt [bh][d][t]. 64x64 LDS tile, pad-67 stride.
// grid (32, 32), block 256.
// ---------------------------------------------------------------------------
__global__ __launch_bounds__(256) void vtrans_kernel(
    const __bf16* __restrict__ V, __bf16* __restrict__ Vt)
{
    __shared__ __bf16 T[64 * 67];
    const int bh = blockIdx.y;
    const int t0 = blockIdx.x * 64;
    const int tid = threadIdx.x;
    const int r = tid >> 2;            // t-row 0..63
    const int c = (tid & 3) * 16;      // d-col base
    const __bf16* src = V + ((size_t)bh * TSEQ + t0 + r) * HDIM + c;
    bf16x8 a = *(const bf16x8*)src;
    bf16x8 b = *(const bf16x8*)(src + 8);
    #pragma unroll
    for (int j = 0; j < 8; ++j) {
        T[r * 67 + c + j] = a[j];
        T[r * 67 + c + 8 + j] = b[j];
    }
    __syncthreads();
    const int dr = tid >> 2;           // d-row 0..63
    const int tc = (tid & 3) * 16;     // t-col base
    bf16x8 o0, o1;
    #pragma unroll
    for (int j = 0; j < 8; ++j) {
        o0[j] = T[(tc + j) * 67 + dr];
        o1[j] = T[(tc + 8 + j) * 67 + dr];
    }
    __bf16* dst = Vt + ((size_t)bh * HDIM + dr) * TSEQ + t0 + tc;
    *(bf16x8*)dst = o0;
    *(bf16x8*)(dst + 8) = o1;
}

// ---------------------------------------------------------------------------
// MFMA flash attention v6: ksplit=4, no running max. Full double-buffer
// (Ks+Vs) -> ONE barrier per 64-key tile; stage(k+1) issued right after the
// barrier (next barrier's vmcnt(0) covers completion). l computed via extra
// PV MFMAs against a constant ones-B-fragment (lands in Oacc row layout; no
// cross-lane reduce). LDS 40KB. Block: 4 waves x 32 q. grid (16,32,4).
// ---------------------------------------------------------------------------
__global__ __launch_bounds__(256, 4) void attn_mfma_kernel(
    const __bf16* __restrict__ Q, const __bf16* __restrict__ K,
    const __bf16* __restrict__ Vt,
    __bf16* __restrict__ O0, __bf16* __restrict__ O1,
    __bf16* __restrict__ O2, __bf16* __restrict__ O3,
    float* __restrict__ L0, float* __restrict__ L1,
    float* __restrict__ L2, float* __restrict__ L3)
{
    __shared__ __align__(16) __bf16 Ks[2][64 * 64];     // 16KB
    __shared__ __align__(16) __bf16 Vs[2][64 * 64];     // 16KB
    __shared__ __align__(16) __bf16 Ps[4][16 * 64];     // 8KB

    const int tid  = threadIdx.x;
    const int wave = tid >> 6;
    const int lane = tid & 63;
    const int l16  = lane & 15;
    const int quad = lane >> 4;
    const int bh   = blockIdx.y;
    const int z    = blockIdx.z;
    const int q0   = blockIdx.x * 128 + wave * 32;
    const int kbase0 = z * (TSEQ / KSPLIT);

    __bf16* __restrict__ Opart = (z == 0) ? O0 : (z == 1) ? O1 : (z == 2) ? O2 : O3;
    float*  __restrict__ Lpart = (z == 0) ? L0 : (z == 1) ? L1 : (z == 2) ? L2 : L3;

    bf16x8 qf[2][2];
    #pragma unroll
    for (int mq = 0; mq < 2; ++mq) {
        const __bf16* Qrow = Q + ((size_t)bh * TSEQ + q0 + mq * 16 + l16) * HDIM;
        qf[mq][0] = *(const bf16x8*)(Qrow + quad * 8);
        qf[mq][1] = *(const bf16x8*)(Qrow + 32 + quad * 8);
    }

    f32x4 Oacc[2][4];
    f32x4 Lacc[2];
    #pragma unroll
    for (int mq = 0; mq < 2; ++mq) {
        #pragma unroll
        for (int dt = 0; dt < 4; ++dt)
            #pragma unroll
            for (int r = 0; r < 4; ++r) Oacc[mq][dt][r] = 0.f;
        #pragma unroll
        for (int r = 0; r < 4; ++r) Lacc[mq][r] = 0.f;
    }

    const __bf16 one_b = (__bf16)1.0f;
    const bf16x8 ones = { one_b, one_b, one_b, one_b,
                          one_b, one_b, one_b, one_b };

    const __bf16* Kbase = K + ((size_t)bh * TSEQ + kbase0) * HDIM;
    const __bf16* Vbase = Vt + (size_t)bh * HDIM * TSEQ + kbase0;

    int srow[2], schk[2];
    #pragma unroll
    for (int i = 0; i < 2; ++i) {
        const int s = wave * 2 + i;
        srow[i] = s * 8 + (lane >> 3);
        schk[i] = (lane & 7) ^ (srow[i] & 7);
    }

#define STAGE(buf, kt)                                                        \
    {                                                                         \
        _Pragma("unroll")                                                     \
        for (int i = 0; i < 2; ++i) {                                         \
            const int s = wave * 2 + i;                                       \
            gload_lds16(Kbase + (size_t)((kt) * 64 + srow[i]) * HDIM          \
                            + schk[i] * 8,                                    \
                        &Ks[buf][s * 512]);                                   \
            gload_lds16(Vbase + (size_t)srow[i] * TSEQ + (kt) * 64            \
                            + schk[i] * 8,                                    \
                        &Vs[buf][s * 512]);                                   \
        }                                                                     \
    }

    STAGE(0, 0);

    #pragma unroll 2
    for (int kt = 0; kt < NT; ++kt) {
        const int buf = kt & 1;
        __syncthreads();                   // stage(kt) done; prior reads done
        if (kt + 1 < NT) STAGE(buf ^ 1, kt + 1);

        // K fragments -> registers (A-operand of S^T = K Q^T)
        bf16x8 kf[4][2];
        #pragma unroll
        for (int nt = 0; nt < 4; ++nt) {
            const int row = nt * 16 + l16;
            #pragma unroll
            for (int ch = 0; ch < 2; ++ch) {
                const int c = (quad + 4 * ch) ^ (row & 7);
                kf[nt][ch] = *(const bf16x8*)(&Ks[buf][row * 64 + c * 8]);
            }
        }

        // S^T + exp + P round-trip, sequential per mq; l via ones-MFMA
        bf16x8 pa[2][2];
        #pragma unroll
        for (int mq = 0; mq < 2; ++mq) {
            #pragma unroll
            for (int nt = 0; nt < 4; ++nt) {
                f32x4 s = {0.f, 0.f, 0.f, 0.f};
                s = __builtin_amdgcn_mfma_f32_16x16x32_bf16(kf[nt][0], qf[mq][0], s, 0, 0, 0);
                s = __builtin_amdgcn_mfma_f32_16x16x32_bf16(kf[nt][1], qf[mq][1], s, 0, 0, 0);
                bf16x4 pk = { (__bf16)exp2f(s[0]), (__bf16)exp2f(s[1]),
                              (__bf16)exp2f(s[2]), (__bf16)exp2f(s[3]) };
                const int kidx = nt * 16 + quad * 4;
                const int pos = ((kidx >> 3) ^ (l16 & 7)) * 8 + (kidx & 7);
                *(bf16x4*)(&Ps[wave][l16 * 64 + pos]) = pk;
            }
            #pragma unroll
            for (int h = 0; h < 2; ++h) {
                const int c = (quad + 4 * h) ^ (l16 & 7);
                pa[mq][h] = *(const bf16x8*)(&Ps[wave][l16 * 64 + c * 8]);
            }
            Lacc[mq] = __builtin_amdgcn_mfma_f32_16x16x32_bf16(
                pa[mq][0], ones, Lacc[mq], 0, 0, 0);
            Lacc[mq] = __builtin_amdgcn_mfma_f32_16x16x32_bf16(
                pa[mq][1], ones, Lacc[mq], 0, 0, 0);
        }

        // PV (V fragments loaded just-in-time from Vs[buf])
        #pragma unroll
        for (int dt = 0; dt < 4; ++dt) {
            const int row = dt * 16 + l16;
            const int c0 = quad ^ (row & 7);
            const int c1 = (quad + 4) ^ (row & 7);
            bf16x8 v0 = *(const bf16x8*)(&Vs[buf][row * 64 + c0 * 8]);
            bf16x8 v1 = *(const bf16x8*)(&Vs[buf][row * 64 + c1 * 8]);
            #pragma unroll
            for (int mq = 0; mq < 2; ++mq) {
                Oacc[mq][dt] = __builtin_amdgcn_mfma_f32_16x16x32_bf16(
                    pa[mq][0], v0, Oacc[mq][dt], 0, 0, 0);
                Oacc[mq][dt] = __builtin_amdgcn_mfma_f32_16x16x32_bf16(
                    pa[mq][1], v1, Oacc[mq][dt], 0, 0, 0);
            }
        }
    }
#undef STAGE

    // Lacc[mq][r] = l for q-row mq*16+quad*4+r (same across l16): one lane col
    #pragma unroll
    for (int mq = 0; mq < 2; ++mq)
        if (l16 == 0) {
            #pragma unroll
            for (int r = 0; r < 4; ++r)
                Lpart[(size_t)bh * TSEQ + q0 + mq * 16 + quad * 4 + r] =
                    Lacc[mq][r];
        }

    // unnormalized O partial, bf16, [bh][t][d] flat
    const size_t base = ((size_t)bh * TSEQ + q0) * HDIM;
    #pragma unroll
    for (int mq = 0; mq < 2; ++mq)
        #pragma unroll
        for (int dt = 0; dt < 4; ++dt)
            #pragma unroll
            for (int r = 0; r < 4; ++r) {
                const size_t idx = base +
                    (size_t)(mq * 16 + quad * 4 + r) * HDIM + dt * 16 + l16;
                Opart[idx] = (__bf16)Oacc[mq][dt][r];
            }
}

// ---------------------------------------------------------------------------
// combine 4 key-split partials: Ob = sum(Oi) / sum(li), bf16 out. grid 2048
// ---------------------------------------------------------------------------
__global__ __launch_bounds__(256) void normalize_kernel(
    const __bf16* __restrict__ O0, const __bf16* __restrict__ O1,
    const __bf16* __restrict__ O2, const __bf16* __restrict__ O3,
    const float* __restrict__ L0, const float* __restrict__ L1,
    const float* __restrict__ L2, const float* __restrict__ L3,
    __bf16* __restrict__ Ob)
{
    const size_t gid = (size_t)blockIdx.x * 256 + threadIdx.x;
    const size_t idx = gid * 8;
    const size_t qi = idx >> 6;
    const float inv = 1.f / (L0[qi] + L1[qi] + L2[qi] + L3[qi]);
    bf16x8 a = *(const bf16x8*)(O0 + idx);
    bf16x8 b = *(const bf16x8*)(O1 + idx);
    bf16x8 c = *(const bf16x8*)(O2 + idx);
    bf16x8 d = *(const bf16x8*)(O3 + idx);
    bf16x8 o;
    #pragma unroll
    for (int j = 0; j < 8; ++j)
        o[j] = (__bf16)((((float)a[j] + (float)b[j]) +
                         ((float)c[j] + (float)d[j])) * inv);
    *(bf16x8*)(Ob + idx) = o;
}

// ---------------------------------------------------------------------------
// plain bf16 MFMA GEMM for out-projection. BM=BN=64, BK=64, 4 waves as 2x2
// of 32x32. Epilogue +bias, fp32 store. grid (16, 64) = 1024 blocks.
// ---------------------------------------------------------------------------
__global__ __launch_bounds__(256) void gemm_out_kernel(
    const __bf16* __restrict__ A, const __bf16* __restrict__ BT,
    const float* __restrict__ bias, float* __restrict__ out)
{
    __shared__ __align__(16) __bf16 As[64 * 64];
    __shared__ __align__(16) __bf16 Bs[64 * 64];
    const int tid = threadIdx.x;
    const int wave = tid >> 6, lane = tid & 63;
    const int l16 = lane & 15, quad = lane >> 4;
    const int wm = wave >> 1, wn = wave & 1;
    const int m0 = blockIdx.y * 64, n0 = blockIdx.x * 64;

    f32x4 acc[2][2];
    #pragma unroll
    for (int mt = 0; mt < 2; ++mt)
        #pragma unroll
        for (int nt = 0; nt < 2; ++nt)
            #pragma unroll
            for (int r = 0; r < 4; ++r) acc[mt][nt][r] = 0.f;

    int srow[2], schk[2], sbase[2];
    #pragma unroll
    for (int i = 0; i < 2; ++i) {
        const int s = wave * 2 + i;
        srow[i] = s * 8 + (lane >> 3);
        schk[i] = (lane & 7) ^ (srow[i] & 7);
        sbase[i] = s * 512;
    }

    for (int k0 = 0; k0 < 1024; k0 += 64) {
        #pragma unroll
        for (int i = 0; i < 2; ++i) {
            gload_lds16(A + (size_t)(m0 + srow[i]) * 1024 + k0 + schk[i] * 8,
                        As + sbase[i]);
            gload_lds16(BT + (size_t)(n0 + srow[i]) * 1024 + k0 + schk[i] * 8,
                        Bs + sbase[i]);
        }
        __syncthreads();
        #pragma unroll
        for (int kk = 0; kk < 2; ++kk) {
            bf16x8 am[2], bn[2];
            #pragma unroll
            for (int mt = 0; mt < 2; ++mt) {
                int row = wm * 32 + mt * 16 + l16;
                int c = (kk * 4 + quad) ^ (row & 7);
                am[mt] = *(const bf16x8*)(As + row * 64 + c * 8);
            }
            #pragma unroll
            for (int nt = 0; nt < 2; ++nt) {
                int row = wn * 32 + nt * 16 + l16;
                int c = (kk * 4 + quad) ^ (row & 7);
                bn[nt] = *(const bf16x8*)(Bs + row * 64 + c * 8);
            }
            #pragma unroll
            for (int mt = 0; mt < 2; ++mt)
                #pragma unroll
                for (int nt = 0; nt < 2; ++nt)
                    acc[mt][nt] = __builtin_amdgcn_mfma_f32_16x16x32_bf16(
                        am[mt], bn[nt], acc[mt][nt], 0, 0, 0);
        }
        __syncthreads();
    }

    #pragma unroll
    for (int nt = 0; nt < 2; ++nt) {
        const int col = n0 + wn * 32 + nt * 16 + l16;
        const float bv = bias[col];
        #pragma unroll
        for (int mt = 0; mt < 2; ++mt)
            #pragma unroll
            for (int r = 0; r < 4; ++r) {
                const int row = m0 + wm * 32 + mt * 16 + quad * 4 + r;
                out[(size_t)row * 1024 + col] = acc[mt][nt][r] + bv;
            }
    }
}

// ---------------------------------------------------------------------------
extern "C" void kernel_launch(void* const* d_in, const int* in_sizes, int n_in,
                              void* d_out, int out_size, void* d_ws, size_t ws_size,
                              hipStream_t stream) {
    const float* x     = (const float*)d_in[0];   // (2048, 2, 1024)
    const float* w_in  = (const float*)d_in[1];   // (1024, 3072)
    const float* b_in  = (const float*)d_in[2];   // (3072,)
    const float* w_out = (const float*)d_in[3];   // (1024, 1024)
    const float* b_out = (const float*)d_in[4];   // (1024,)
    float* out = (float*)d_out;                   // (2, 2048, 1024) flat 4096x1024

    const size_t M1 = (size_t)1024 * 1024;
    __bf16* ws  = (__bf16*)d_ws;
    __bf16* xb  = ws;                 // 4M elem
    __bf16* wiT = xb  + 4 * M1;       // 3M
    __bf16* whT = wiT + 3 * M1;       // 1M
    __bf16* Qb  = whT + 1 * M1;       // 4M
    __bf16* Kb  = Qb  + 4 * M1;       // 4M
    __bf16* Vt  = Kb  + 4 * M1;       // 4M
    __bf16* O0  = Vt  + 4 * M1;       // 4M (bf16 unnormalized partial)
    __bf16* O1  = O0  + 4 * M1;       // 4M
    float*  L0  = (float*)(O1 + 4 * M1);          // 4 x 64K floats
    float*  L1  = L0 + 65536;
    float*  L2  = L1 + 65536;
    float*  L3  = L2 + 65536;
    // d_out (16MB = 8M bf16) dead until gemm_out: park Vb then O2/O3 there.
    __bf16* Vb  = (__bf16*)d_out;
    __bf16* O2  = (__bf16*)d_out;
    __bf16* O3  = O2 + 4 * M1;
    __bf16* Ob  = xb;                 // alias: xb dead after gemm_qkv

    prep_kernel<<<dim3(256, 32), dim3(32, 8), 0, stream>>>(
        x, w_in, w_out, xb, wiT, whT);
    gemm_qkv_kernel<<<dim3(24, 32), 256, 0, stream>>>(
        xb, wiT, b_in, Qb, Kb, Vb);
    vtrans_kernel<<<dim3(32, 32), 256, 0, stream>>>(Vb, Vt);
    attn_mfma_kernel<<<dim3(16, 32, KSPLIT), 256, 0, stream>>>(
        Qb, Kb, Vt, O0, O1, O2, O3, L0, L1, L2, L3);
    normalize_kernel<<<2048, 256, 0, stream>>>(
        O0, O1, O2, O3, L0, L1, L2, L3, Ob);
    gemm_out_kernel<<<dim3(16, 64), 256, 0, stream>>>(
        Ob, whT, b_out, out);
}